// Round 11
// baseline (192.582 us; speedup 1.0000x reference)
//
#include <hip/hip_runtime.h>
#include <hip/hip_bf16.h>
#include <hip/hip_fp16.h>
#include <math.h>

#define B 8
#define C 256
#define HH 64
#define WW 64
#define NN 4096      // H*W
#define CI 128
#define NS 1024      // pooled spatial
#define EPS 1e-5f

typedef __attribute__((ext_vector_type(8))) _Float16 f16x8;
typedef __attribute__((ext_vector_type(4))) float f32x4;

static __device__ __forceinline__ unsigned short f2h_bits(float f) {
    return __half_as_ushort(__float2half(f));   // v_cvt_f16_f32 (RNE)
}
static __device__ __forceinline__ float h2f(unsigned short u) {
    return __half2float(__ushort_as_half(u));
}

// ---------------------------------------------------------------- K0: x transpose->f16 (+ weight prep folded in)
__global__ __launch_bounds__(256) void k_xt(const float* __restrict__ x,
        unsigned short* __restrict__ xh,
        const float* __restrict__ tw, const float* __restrict__ pw,
        const float* __restrict__ gw, const float* __restrict__ ww,
        unsigned short* __restrict__ wh) {
    int tid = threadIdx.x;
    if (blockIdx.x == 64) {   // weight prep: 32 instances x 4096 elements
        int inst = blockIdx.y * B + blockIdx.z;       // 0..31
        int base = inst * 4096;
        #pragma unroll
        for (int k = 0; k < 16; ++k) {
            int idx = base + tid + k * 256;           // 0..131071
            int sel = idx >> 15, off = idx & 32767;
            const float* src = (sel == 0) ? tw : (sel == 1) ? pw : (sel == 2) ? gw : ww;
            wh[idx] = f2h_bits(src[off]);
        }
        return;
    }
    __shared__ float s_t[64 * 65];
    int n0 = blockIdx.x * 64;
    int c0 = blockIdx.y * 64;
    int b  = blockIdx.z;
    #pragma unroll
    for (int k = 0; k < 16; ++k) {
        int idx = tid + k * 256;           // 0..4095
        int cl = idx >> 6, nl = idx & 63;
        s_t[cl * 65 + nl] = x[((size_t)b * C + c0 + cl) * NN + n0 + nl];
    }
    __syncthreads();
    #pragma unroll
    for (int k = 0; k < 8; ++k) {
        int idx = tid + k * 256;           // 0..2047
        int nl = idx >> 5, cp = (idx & 31) * 2;
        ushort2 o;
        o.x = f2h_bits(s_t[cp * 65 + nl]);
        o.y = f2h_bits(s_t[(cp + 1) * 65 + nl]);
        *(ushort2*)&xh[((size_t)b * NN + n0 + nl) * C + c0 + cp] = o;
    }
}

// ---------------------------------------------------------------- K1: fused theta + pooled phi/g convs (MFMA)
__global__ __launch_bounds__(512) void k_convs(const unsigned short* __restrict__ xh,
        const unsigned short* __restrict__ twh, const unsigned short* __restrict__ pwh,
        const unsigned short* __restrict__ gwh,
        const float* __restrict__ tb, const float* __restrict__ pb, const float* __restrict__ gb_,
        unsigned short* __restrict__ theta, unsigned short* __restrict__ phi,
        unsigned short* __restrict__ gout) {
    int blk = blockIdx.x;                 // 256 blocks
    int b   = blk >> 5;
    int mh  = blk & 31;                   // pooled h row
    int tid = threadIdx.x;
    int lane = tid & 63, wv = tid >> 6;
    int lr = lane & 15, lh = lane >> 4;
    int wn = wv & 3, wc = wv >> 2;
    size_t row0 = (size_t)blk * 128;

    f32x4 accT[8];
    f32x4 aP0[4], aP1[4], aG0[4], aG1[4];
    #pragma unroll
    for (int i = 0; i < 8; ++i) accT[i] = (f32x4){0,0,0,0};
    #pragma unroll
    for (int i = 0; i < 4; ++i) {
        aP0[i] = (f32x4){0,0,0,0}; aP1[i] = (f32x4){0,0,0,0};
        aG0[i] = (f32x4){0,0,0,0}; aG1[i] = (f32x4){0,0,0,0};
    }

    const unsigned short* ap0 = xh + (row0 + wn * 16 + lr) * C + lh * 8;
    const unsigned short* ap1 = ap0 + (size_t)64 * C;
    #pragma unroll
    for (int kc = 0; kc < 8; ++kc) {
        f16x8 a0 = *(const f16x8*)(ap0 + kc * 32);
        f16x8 a1 = *(const f16x8*)(ap1 + kc * 32);
        f16x8 aT = (wv < 4) ? a0 : a1;
        #pragma unroll
        for (int ct = 0; ct < 8; ++ct) {
            f16x8 bt_ = *(const f16x8*)&twh[(ct * 16 + lr) * C + kc * 32 + lh * 8];
            accT[ct] = __builtin_amdgcn_mfma_f32_16x16x32_f16(aT, bt_, accT[ct], 0, 0, 0);
        }
        #pragma unroll
        for (int ct = 0; ct < 4; ++ct) {
            int wrow = (wc * 64 + ct * 16 + lr) * C + kc * 32 + lh * 8;
            f16x8 bp = *(const f16x8*)&pwh[wrow];
            f16x8 bg = *(const f16x8*)&gwh[wrow];
            aP0[ct] = __builtin_amdgcn_mfma_f32_16x16x32_f16(a0, bp, aP0[ct], 0, 0, 0);
            aP1[ct] = __builtin_amdgcn_mfma_f32_16x16x32_f16(a1, bp, aP1[ct], 0, 0, 0);
            aG0[ct] = __builtin_amdgcn_mfma_f32_16x16x32_f16(a0, bg, aG0[ct], 0, 0, 0);
            aG1[ct] = __builtin_amdgcn_mfma_f32_16x16x32_f16(a1, bg, aG1[ct], 0, 0, 0);
        }
    }
    #pragma unroll
    for (int ct = 0; ct < 8; ++ct) {
        int ci = ct * 16 + lr;
        float bias = tb[ci];
        #pragma unroll
        for (int r = 0; r < 4; ++r)
            theta[(row0 + wv * 16 + lh * 4 + r) * CI + ci] = f2h_bits(accT[ct][r] + bias);
    }
    #pragma unroll
    for (int ct = 0; ct < 4; ++ct) {
        int ci = wc * 64 + ct * 16 + lr;
        float biasP = pb[ci], biasG = gb_[ci];
        #pragma unroll
        for (int j = 0; j < 2; ++j) {
            int m = mh * 32 + wn * 8 + lh * 2 + j;
            float vP = fmaxf(fmaxf(aP0[ct][2*j], aP0[ct][2*j+1]),
                             fmaxf(aP1[ct][2*j], aP1[ct][2*j+1])) + biasP;
            float vG = fmaxf(fmaxf(aG0[ct][2*j], aG0[ct][2*j+1]),
                             fmaxf(aG1[ct][2*j], aG1[ct][2*j+1])) + biasG;
            phi[((size_t)b * NS + m) * CI + ci]  = f2h_bits(vP);
            gout[((size_t)b * CI + ci) * NS + m] = f2h_bits(vG);
        }
    }
}

// ---------------------------------------------------------------- K3: fused attention v5
// r5-proven structure (16x16x32, single-buffer LDS, 2 barriers/tile) + flash-decoding
// m-split across blocks (blockIdx.z = half). Emits UNNORMALIZED partials (f16, P<=1 so
// |yacc| <= 1024*|g|, no overflow) + per-row (m,l) float2. Combine is fused into k_wconv.
#define SPH 136   // 128+8 f16 row stride
#define SG  72    // 64+8 f16
#define SP  72
__global__ __launch_bounds__(256) void k_attn_mfma(const unsigned short* __restrict__ theta,
        const unsigned short* __restrict__ phi, const unsigned short* __restrict__ g,
        unsigned short* __restrict__ yp, float2* __restrict__ ml) {
    __shared__ unsigned short s_ph[64 * SPH];   // 17408 B
    __shared__ unsigned short s_g[128 * SG];    // 18432 B
    __shared__ unsigned short s_p[64 * SP];     //  9216 B   (45056 B -> 3 blocks/CU)
    int rb = blockIdx.x;               // 64 row-blocks of 64
    int b  = blockIdx.y;
    int sx = blockIdx.z;               // m-half: tiles sx*8 .. sx*8+7
    int tid = threadIdx.x;
    int lane = tid & 63, wv = tid >> 6;
    int lr = lane & 15, lh = lane >> 4;
    int row0 = rb * 64;
    int wrow = wv * 16;

    f16x8 a_th[4];
    {
        const unsigned short* tp = theta + ((size_t)b * NN + row0 + wrow + lr) * CI + lh * 8;
        #pragma unroll
        for (int kc = 0; kc < 4; ++kc) a_th[kc] = *(const f16x8*)(tp + kc * 32);
    }

    f32x4 yacc[8];
    #pragma unroll
    for (int i = 0; i < 8; ++i) yacc[i] = (f32x4){0.f, 0.f, 0.f, 0.f};
    float mrun[4] = {-1e30f, -1e30f, -1e30f, -1e30f};
    float lrun[4] = {0.f, 0.f, 0.f, 0.f};

    for (int t = 0; t < 8; ++t) {
        int mt = sx * 8 + t;
        __syncthreads();   // protect s_ph/s_g from previous-iter readers
        {   // stage phi tile: 64 rows x 128 f16 (32 ushort4/row)
            const ushort4* src = (const ushort4*)(phi + ((size_t)b * NS + mt * 64) * CI);
            #pragma unroll
            for (int k = 0; k < 8; ++k) {
                int tt = tid + k * 256;        // 0..2047
                int r = tt >> 5, cq = tt & 31;
                ushort4 vv = src[r * 32 + cq];
                *(ushort4*)&s_ph[r * SPH + cq * 4] = vv;
            }
            // stage g tile: 128 ci-rows x 64 m (16 ushort4/row)
            const ushort4* sg = (const ushort4*)(g + (size_t)b * CI * NS);
            #pragma unroll
            for (int k = 0; k < 8; ++k) {
                int tt = tid + k * 256;
                int ci = tt >> 4, cq = tt & 15;
                ushort4 vv = sg[ci * 256 + mt * 16 + cq];
                *(ushort4*)&s_g[ci * SG + cq * 4] = vv;
            }
        }
        __syncthreads();

        // ---- S = theta * phi^T
        f32x4 S[4];
        #pragma unroll
        for (int nt = 0; nt < 4; ++nt) S[nt] = (f32x4){0.f, 0.f, 0.f, 0.f};
        #pragma unroll
        for (int nt = 0; nt < 4; ++nt) {
            #pragma unroll
            for (int kc = 0; kc < 4; ++kc) {
                f16x8 bf = *(const f16x8*)&s_ph[(nt * 16 + lr) * SPH + kc * 32 + lh * 8];
                S[nt] = __builtin_amdgcn_mfma_f32_16x16x32_f16(a_th[kc], bf, S[nt], 0, 0, 0);
            }
        }

        // ---- online softmax (rows lh*4+r; 16-lane col groups)
        float rmax[4], rs[4], scale[4];
        #pragma unroll
        for (int r = 0; r < 4; ++r)
            rmax[r] = fmaxf(fmaxf(S[0][r], S[1][r]), fmaxf(S[2][r], S[3][r]));
        #pragma unroll
        for (int s = 1; s < 16; s <<= 1) {
            #pragma unroll
            for (int r = 0; r < 4; ++r) rmax[r] = fmaxf(rmax[r], __shfl_xor(rmax[r], s));
        }
        #pragma unroll
        for (int r = 0; r < 4; ++r) {
            float mnew = fmaxf(mrun[r], rmax[r]);
            scale[r] = __expf(mrun[r] - mnew);
            mrun[r] = mnew;
            rs[r] = 0.f;
        }
        #pragma unroll
        for (int nt = 0; nt < 4; ++nt) {
            #pragma unroll
            for (int r = 0; r < 4; ++r) {
                float e = __expf(S[nt][r] - mrun[r]);
                S[nt][r] = e;
                rs[r] += e;
            }
        }
        #pragma unroll
        for (int s = 1; s < 16; s <<= 1) {
            #pragma unroll
            for (int r = 0; r < 4; ++r) rs[r] += __shfl_xor(rs[r], s);
        }
        #pragma unroll
        for (int r = 0; r < 4; ++r) lrun[r] = lrun[r] * scale[r] + rs[r];
        #pragma unroll
        for (int i = 0; i < 8; ++i) {
            #pragma unroll
            for (int r = 0; r < 4; ++r) yacc[i][r] *= scale[r];
        }
        // P -> wave-private LDS rows (same wave reads back; no barrier)
        #pragma unroll
        for (int nt = 0; nt < 4; ++nt) {
            #pragma unroll
            for (int r = 0; r < 4; ++r)
                s_p[(wrow + lh * 4 + r) * SP + nt * 16 + lr] = f2h_bits(S[nt][r]);
        }

        // ---- y += P * g
        f16x8 a_p[2];
        #pragma unroll
        for (int kc = 0; kc < 2; ++kc)
            a_p[kc] = *(const f16x8*)&s_p[(wrow + lr) * SP + kc * 32 + lh * 8];
        #pragma unroll
        for (int ct = 0; ct < 8; ++ct) {
            #pragma unroll
            for (int kc = 0; kc < 2; ++kc) {
                f16x8 bg = *(const f16x8*)&s_g[(ct * 16 + lr) * SG + kc * 32 + lh * 8];
                yacc[ct] = __builtin_amdgcn_mfma_f32_16x16x32_f16(a_p[kc], bg, yacc[ct], 0, 0, 0);
            }
        }
    }

    // ---- write unnormalized partial + (m,l) per row
    size_t pbase = ((size_t)(sx * B + b) * NN + row0 + wrow);
    #pragma unroll
    for (int ct = 0; ct < 8; ++ct) {
        #pragma unroll
        for (int r = 0; r < 4; ++r)
            yp[(pbase + lh * 4 + r) * CI + ct * 16 + lr] = f2h_bits(yacc[ct][r]);
    }
    if (lr == 0) {
        #pragma unroll
        for (int r = 0; r < 4; ++r) {
            float2 v; v.x = mrun[r]; v.y = lrun[r];
            ml[pbase + lh * 4 + r] = v;
        }
    }
}

// ---------------------------------------------------------------- K4: W conv (MFMA) + fused flash combine -> f16 wy + BN partials
__global__ __launch_bounds__(256) void k_wconv(const unsigned short* __restrict__ yp,
        const float2* __restrict__ ml, const unsigned short* __restrict__ wwh,
        const float* __restrict__ wb, unsigned short* __restrict__ wyh,
        float* __restrict__ psum, float* __restrict__ psq) {
    int blk = blockIdx.x;                  // 512 blocks of 64 n
    int b   = blk >> 6;
    int nloc = (blk & 63) * 64;
    int tid = threadIdx.x;
    int lane = tid & 63, wv = tid >> 6;
    int lr = lane & 15, lh = lane >> 4;

    f32x4 acc[4][4];
    #pragma unroll
    for (int i = 0; i < 4; ++i)
        #pragma unroll
        for (int j = 0; j < 4; ++j) acc[i][j] = (f32x4){0.f, 0.f, 0.f, 0.f};

    const unsigned short* y0b = yp + ((size_t)b * NN + nloc) * CI;
    const unsigned short* y1b = yp + ((size_t)(B + b) * NN + nloc) * CI;
    const float2* ml0 = ml + ((size_t)b * NN + nloc);
    const float2* ml1 = ml + ((size_t)(B + b) * NN + nloc);

    // per-row combine factors (row n = bt*16 + lr)
    float a0v[4], a1v[4];
    #pragma unroll
    for (int bt = 0; bt < 4; ++bt) {
        int n = bt * 16 + lr;
        float2 p0 = ml0[n], p1 = ml1[n];
        float M = fmaxf(p0.x, p1.x);
        float e0 = __expf(p0.x - M), e1 = __expf(p1.x - M);
        float L = e0 * p0.y + e1 * p1.y;
        a0v[bt] = e0 / L;
        a1v[bt] = e1 / L;
    }

    #pragma unroll
    for (int kc = 0; kc < 4; ++kc) {
        f16x8 a[4], bf[4];
        #pragma unroll
        for (int at = 0; at < 4; ++at)
            a[at] = *(const f16x8*)&wwh[(wv * 64 + at * 16 + lr) * CI + kc * 32 + lh * 8];
        #pragma unroll
        for (int bt = 0; bt < 4; ++bt) {
            size_t off = (size_t)(bt * 16 + lr) * CI + kc * 32 + lh * 8;
            f16x8 u0 = *(const f16x8*)&y0b[off];
            f16x8 u1 = *(const f16x8*)&y1b[off];
            f16x8 v;
            #pragma unroll
            for (int i = 0; i < 8; ++i)
                v[i] = (_Float16)(a0v[bt] * (float)u0[i] + a1v[bt] * (float)u1[i]);
            bf[bt] = v;
        }
        #pragma unroll
        for (int at = 0; at < 4; ++at)
            #pragma unroll
            for (int bt = 0; bt < 4; ++bt)
                acc[at][bt] = __builtin_amdgcn_mfma_f32_16x16x32_f16(a[at], bf[bt], acc[at][bt], 0, 0, 0);
    }
    #pragma unroll
    for (int at = 0; at < 4; ++at) {
        #pragma unroll
        for (int r = 0; r < 4; ++r) {
            int co = wv * 64 + at * 16 + lh * 4 + r;
            float bias = wb[co];
            unsigned short* wp = wyh + ((size_t)b * C + co) * NN + nloc;
            float sv = 0.f, q = 0.f;
            #pragma unroll
            for (int bt = 0; bt < 4; ++bt) {
                float v = acc[at][bt][r] + bias;
                wp[bt * 16 + lr] = f2h_bits(v);
                sv += v;
                q = fmaf(v, v, q);
            }
            #pragma unroll
            for (int o = 1; o < 16; o <<= 1) {
                sv += __shfl_xor(sv, o);
                q  += __shfl_xor(q, o);
            }
            if (lr == 0) {
                psum[co * 512 + blk] = sv;
                psq[co * 512 + blk]  = q;
            }
        }
    }
}

// ---------------------------------------------------------------- K4b: reduce BN partials
__global__ __launch_bounds__(64) void k_stats_r(const float* __restrict__ psum,
        const float* __restrict__ psq, float* __restrict__ stats) {
    int c = blockIdx.x;
    int lane = threadIdx.x;
    float s = 0.f, q = 0.f;
    #pragma unroll
    for (int k = 0; k < 8; ++k) {
        s += psum[c * 512 + lane + k * 64];
        q += psq[c * 512 + lane + k * 64];
    }
    #pragma unroll
    for (int o = 32; o >= 1; o >>= 1) {
        s += __shfl_down(s, o);
        q += __shfl_down(q, o);
    }
    if (lane == 0) { stats[c] = s; stats[256 + c] = q; }
}

// ---------------------------------------------------------------- K5: BN apply + residual (f16 wy input)
__global__ __launch_bounds__(256) void k_bn_out(const unsigned short* __restrict__ wyh,
        const float* __restrict__ x, const float* __restrict__ stats,
        const float* __restrict__ gamma, const float* __restrict__ beta,
        float* __restrict__ out) {
    size_t t = (size_t)blockIdx.x * 256 + threadIdx.x;   // 8-element groups
    size_t base = t * 8;
    int c = (int)((base >> 12) & 255);
    float mean = stats[c] * (1.f / 32768.f);
    float var  = stats[256 + c] * (1.f / 32768.f) - mean * mean;
    float sc = gamma[c] * rsqrtf(var + EPS);
    float sh = beta[c] - mean * sc;
    ushort4 w0 = *(const ushort4*)&wyh[base];
    ushort4 w1 = *(const ushort4*)&wyh[base + 4];
    float4 x0 = *(const float4*)&x[base];
    float4 x1 = *(const float4*)&x[base + 4];
    float4 o0, o1;
    o0.x = fmaf(h2f(w0.x), sc, sh) + x0.x;
    o0.y = fmaf(h2f(w0.y), sc, sh) + x0.y;
    o0.z = fmaf(h2f(w0.z), sc, sh) + x0.z;
    o0.w = fmaf(h2f(w0.w), sc, sh) + x0.w;
    o1.x = fmaf(h2f(w1.x), sc, sh) + x1.x;
    o1.y = fmaf(h2f(w1.y), sc, sh) + x1.y;
    o1.z = fmaf(h2f(w1.z), sc, sh) + x1.z;
    o1.w = fmaf(h2f(w1.w), sc, sh) + x1.w;
    *(float4*)&out[base]     = o0;
    *(float4*)&out[base + 4] = o1;
}

// ----------------------------------------------------------------
extern "C" void kernel_launch(void* const* d_in, const int* in_sizes, int n_in,
                              void* d_out, int out_size, void* d_ws, size_t ws_size,
                              hipStream_t stream) {
    const float* x    = (const float*)d_in[0];
    const float* g_w  = (const float*)d_in[1];
    const float* g_b  = (const float*)d_in[2];
    const float* th_w = (const float*)d_in[3];
    const float* th_b = (const float*)d_in[4];
    const float* ph_w = (const float*)d_in[5];
    const float* ph_b = (const float*)d_in[6];
    const float* w_w  = (const float*)d_in[7];
    const float* w_b  = (const float*)d_in[8];
    const float* bn_g = (const float*)d_in[9];
    const float* bn_b = (const float*)d_in[10];
    float* out = (float*)d_out;

    char* w0 = (char*)d_ws;
    unsigned short* xh    = (unsigned short*)w0;                 // [B][N][C] f16  16,777,216 B (dead after k_convs)
    unsigned short* yp    = (unsigned short*)w0;                 // [2][B][N][CI] f16 16,777,216 B (reuses xh)
    unsigned short* theta = (unsigned short*)(w0 + 16777216);    // [B][N][CI] f16   8,388,608 B
    unsigned short* wh    = (unsigned short*)(w0 + 25165824);    // 4x32768 f16        262,144 B
    unsigned short* twh   = wh;
    unsigned short* pwh   = wh + 32768;
    unsigned short* gwh   = wh + 65536;
    unsigned short* wwh   = wh + 98304;
    unsigned short* phi   = (unsigned short*)(w0 + 25427968);    // [B][m][CI] f16   2,097,152 B
    unsigned short* gx    = (unsigned short*)(w0 + 27525120);    // [B][CI][m] f16   2,097,152 B
    unsigned short* wyh   = (unsigned short*)(w0 + 38010880);    // [B][C][N]  f16  16,777,216 B
    float*          psum  = (float*)(w0 + 54788096);             // [256][512] f32     524,288 B
    float*          psq   = (float*)(w0 + 55312384);             // [256][512] f32     524,288 B
    float*          stats = (float*)(w0 + 55836672);             // 512 f32
    float2*         ml    = (float2*)(w0 + 55840768);            // [2][B][N] float2   524,288 B

    k_xt<<<dim3(65, 4, B), 256, 0, stream>>>(x, xh, th_w, ph_w, g_w, w_w, wh);
    k_convs<<<256, 512, 0, stream>>>(xh, twh, pwh, gwh, th_b, ph_b, g_b, theta, phi, gx);
    k_attn_mfma<<<dim3(64, B, 2), 256, 0, stream>>>(theta, phi, gx, yp, ml);
    k_wconv<<<512, 256, 0, stream>>>(yp, ml, wwh, w_b, wyh, psum, psq);
    k_stats_r<<<256, 64, 0, stream>>>(psum, psq, stats);
    k_bn_out<<<4096, 256, 0, stream>>>(wyh, x, stats, bn_g, bn_b, out);
}

// Round 12
// 135.613 us; speedup vs baseline: 1.4201x; 1.4201x over previous
//
#include <hip/hip_runtime.h>
#include <hip/hip_bf16.h>
#include <hip/hip_fp16.h>
#include <math.h>

#define B 8
#define C 256
#define HH 64
#define WW 64
#define NN 4096      // H*W
#define CI 128
#define NS 1024      // pooled spatial
#define EPS 1e-5f

typedef __attribute__((ext_vector_type(8))) _Float16 f16x8;
typedef __attribute__((ext_vector_type(4))) float f32x4;

static __device__ __forceinline__ unsigned short f2h_bits(float f) {
    return __half_as_ushort(__float2half(f));   // v_cvt_f16_f32 (RNE)
}
static __device__ __forceinline__ float h2f(unsigned short u) {
    return __half2float(__ushort_as_half(u));
}

// ---------------------------------------------------------------- K0: x transpose->f16 (+ weight prep folded in)
__global__ __launch_bounds__(256) void k_xt(const float* __restrict__ x,
        unsigned short* __restrict__ xh,
        const float* __restrict__ tw, const float* __restrict__ pw,
        const float* __restrict__ gw, const float* __restrict__ ww,
        unsigned short* __restrict__ wh) {
    int tid = threadIdx.x;
    if (blockIdx.x == 64) {   // weight prep: 32 instances x 4096 elements
        int inst = blockIdx.y * B + blockIdx.z;       // 0..31
        int base = inst * 4096;
        #pragma unroll
        for (int k = 0; k < 16; ++k) {
            int idx = base + tid + k * 256;           // 0..131071
            int sel = idx >> 15, off = idx & 32767;
            const float* src = (sel == 0) ? tw : (sel == 1) ? pw : (sel == 2) ? gw : ww;
            wh[idx] = f2h_bits(src[off]);
        }
        return;
    }
    __shared__ float s_t[64 * 65];
    int n0 = blockIdx.x * 64;
    int c0 = blockIdx.y * 64;
    int b  = blockIdx.z;
    #pragma unroll
    for (int k = 0; k < 16; ++k) {
        int idx = tid + k * 256;           // 0..4095
        int cl = idx >> 6, nl = idx & 63;
        s_t[cl * 65 + nl] = x[((size_t)b * C + c0 + cl) * NN + n0 + nl];
    }
    __syncthreads();
    #pragma unroll
    for (int k = 0; k < 8; ++k) {
        int idx = tid + k * 256;           // 0..2047
        int nl = idx >> 5, cp = (idx & 31) * 2;
        ushort2 o;
        o.x = f2h_bits(s_t[cp * 65 + nl]);
        o.y = f2h_bits(s_t[(cp + 1) * 65 + nl]);
        *(ushort2*)&xh[((size_t)b * NN + n0 + nl) * C + c0 + cp] = o;
    }
}

// ---------------------------------------------------------------- K1: fused theta + pooled phi/g convs (MFMA)
__global__ __launch_bounds__(512) void k_convs(const unsigned short* __restrict__ xh,
        const unsigned short* __restrict__ twh, const unsigned short* __restrict__ pwh,
        const unsigned short* __restrict__ gwh,
        const float* __restrict__ tb, const float* __restrict__ pb, const float* __restrict__ gb_,
        unsigned short* __restrict__ theta, unsigned short* __restrict__ phi,
        unsigned short* __restrict__ gout) {
    int blk = blockIdx.x;                 // 256 blocks
    int b   = blk >> 5;
    int mh  = blk & 31;                   // pooled h row
    int tid = threadIdx.x;
    int lane = tid & 63, wv = tid >> 6;
    int lr = lane & 15, lh = lane >> 4;
    int wn = wv & 3, wc = wv >> 2;
    size_t row0 = (size_t)blk * 128;

    f32x4 accT[8];
    f32x4 aP0[4], aP1[4], aG0[4], aG1[4];
    #pragma unroll
    for (int i = 0; i < 8; ++i) accT[i] = (f32x4){0,0,0,0};
    #pragma unroll
    for (int i = 0; i < 4; ++i) {
        aP0[i] = (f32x4){0,0,0,0}; aP1[i] = (f32x4){0,0,0,0};
        aG0[i] = (f32x4){0,0,0,0}; aG1[i] = (f32x4){0,0,0,0};
    }

    const unsigned short* ap0 = xh + (row0 + wn * 16 + lr) * C + lh * 8;
    const unsigned short* ap1 = ap0 + (size_t)64 * C;
    #pragma unroll
    for (int kc = 0; kc < 8; ++kc) {
        f16x8 a0 = *(const f16x8*)(ap0 + kc * 32);
        f16x8 a1 = *(const f16x8*)(ap1 + kc * 32);
        f16x8 aT = (wv < 4) ? a0 : a1;
        #pragma unroll
        for (int ct = 0; ct < 8; ++ct) {
            f16x8 bt_ = *(const f16x8*)&twh[(ct * 16 + lr) * C + kc * 32 + lh * 8];
            accT[ct] = __builtin_amdgcn_mfma_f32_16x16x32_f16(aT, bt_, accT[ct], 0, 0, 0);
        }
        #pragma unroll
        for (int ct = 0; ct < 4; ++ct) {
            int wrow = (wc * 64 + ct * 16 + lr) * C + kc * 32 + lh * 8;
            f16x8 bp = *(const f16x8*)&pwh[wrow];
            f16x8 bg = *(const f16x8*)&gwh[wrow];
            aP0[ct] = __builtin_amdgcn_mfma_f32_16x16x32_f16(a0, bp, aP0[ct], 0, 0, 0);
            aP1[ct] = __builtin_amdgcn_mfma_f32_16x16x32_f16(a1, bp, aP1[ct], 0, 0, 0);
            aG0[ct] = __builtin_amdgcn_mfma_f32_16x16x32_f16(a0, bg, aG0[ct], 0, 0, 0);
            aG1[ct] = __builtin_amdgcn_mfma_f32_16x16x32_f16(a1, bg, aG1[ct], 0, 0, 0);
        }
    }
    #pragma unroll
    for (int ct = 0; ct < 8; ++ct) {
        int ci = ct * 16 + lr;
        float bias = tb[ci];
        #pragma unroll
        for (int r = 0; r < 4; ++r)
            theta[(row0 + wv * 16 + lh * 4 + r) * CI + ci] = f2h_bits(accT[ct][r] + bias);
    }
    #pragma unroll
    for (int ct = 0; ct < 4; ++ct) {
        int ci = wc * 64 + ct * 16 + lr;
        float biasP = pb[ci], biasG = gb_[ci];
        #pragma unroll
        for (int j = 0; j < 2; ++j) {
            int m = mh * 32 + wn * 8 + lh * 2 + j;
            float vP = fmaxf(fmaxf(aP0[ct][2*j], aP0[ct][2*j+1]),
                             fmaxf(aP1[ct][2*j], aP1[ct][2*j+1])) + biasP;
            float vG = fmaxf(fmaxf(aG0[ct][2*j], aG0[ct][2*j+1]),
                             fmaxf(aG1[ct][2*j], aG1[ct][2*j+1])) + biasG;
            phi[((size_t)b * NS + m) * CI + ci]  = f2h_bits(vP);
            gout[((size_t)b * CI + ci) * NS + m] = f2h_bits(vG);
        }
    }
}

// ---------------------------------------------------------------- K3: fused attention v5b
// r5-proven structure + flash-decoding m-split across blocks (blockIdx.z).
// __launch_bounds__(256,3): LDS 45KB allows 3 blocks/CU (=3 waves/SIMD); declaring it
// gives a 170-VGPR budget so the compiler keeps all 16 staging loads in flight
// (r11's default build chose 84 VGPR targeting an impossible 6 waves/SIMD -> serialized staging).
#define SPH 136   // 128+8 f16 row stride
#define SG  72    // 64+8 f16
#define SP  72
__global__ __launch_bounds__(256, 3) void k_attn_mfma(const unsigned short* __restrict__ theta,
        const unsigned short* __restrict__ phi, const unsigned short* __restrict__ g,
        unsigned short* __restrict__ yp, float2* __restrict__ ml) {
    __shared__ unsigned short s_ph[64 * SPH];   // 17408 B
    __shared__ unsigned short s_g[128 * SG];    // 18432 B
    __shared__ unsigned short s_p[64 * SP];     //  9216 B   (45056 B -> 3 blocks/CU)
    int rb = blockIdx.x;               // 64 row-blocks of 64
    int b  = blockIdx.y;
    int sx = blockIdx.z;               // m-half: tiles sx*8 .. sx*8+7
    int tid = threadIdx.x;
    int lane = tid & 63, wv = tid >> 6;
    int lr = lane & 15, lh = lane >> 4;
    int row0 = rb * 64;
    int wrow = wv * 16;

    f16x8 a_th[4];
    {
        const unsigned short* tp = theta + ((size_t)b * NN + row0 + wrow + lr) * CI + lh * 8;
        #pragma unroll
        for (int kc = 0; kc < 4; ++kc) a_th[kc] = *(const f16x8*)(tp + kc * 32);
    }

    f32x4 yacc[8];
    #pragma unroll
    for (int i = 0; i < 8; ++i) yacc[i] = (f32x4){0.f, 0.f, 0.f, 0.f};
    float mrun[4] = {-1e30f, -1e30f, -1e30f, -1e30f};
    float lrun[4] = {0.f, 0.f, 0.f, 0.f};

    for (int t = 0; t < 8; ++t) {
        int mt = sx * 8 + t;
        __syncthreads();   // protect s_ph/s_g from previous-iter readers
        {   // stage phi tile: 64 rows x 128 f16 (32 ushort4/row)
            const ushort4* src = (const ushort4*)(phi + ((size_t)b * NS + mt * 64) * CI);
            #pragma unroll
            for (int k = 0; k < 8; ++k) {
                int tt = tid + k * 256;        // 0..2047
                int r = tt >> 5, cq = tt & 31;
                ushort4 vv = src[r * 32 + cq];
                *(ushort4*)&s_ph[r * SPH + cq * 4] = vv;
            }
            // stage g tile: 128 ci-rows x 64 m (16 ushort4/row)
            const ushort4* sg = (const ushort4*)(g + (size_t)b * CI * NS);
            #pragma unroll
            for (int k = 0; k < 8; ++k) {
                int tt = tid + k * 256;
                int ci = tt >> 4, cq = tt & 15;
                ushort4 vv = sg[ci * 256 + mt * 16 + cq];
                *(ushort4*)&s_g[ci * SG + cq * 4] = vv;
            }
        }
        __syncthreads();

        // ---- S = theta * phi^T
        f32x4 S[4];
        #pragma unroll
        for (int nt = 0; nt < 4; ++nt) S[nt] = (f32x4){0.f, 0.f, 0.f, 0.f};
        #pragma unroll
        for (int nt = 0; nt < 4; ++nt) {
            #pragma unroll
            for (int kc = 0; kc < 4; ++kc) {
                f16x8 bf = *(const f16x8*)&s_ph[(nt * 16 + lr) * SPH + kc * 32 + lh * 8];
                S[nt] = __builtin_amdgcn_mfma_f32_16x16x32_f16(a_th[kc], bf, S[nt], 0, 0, 0);
            }
        }

        // ---- online softmax (rows lh*4+r; 16-lane col groups)
        float rmax[4], rs[4], scale[4];
        #pragma unroll
        for (int r = 0; r < 4; ++r)
            rmax[r] = fmaxf(fmaxf(S[0][r], S[1][r]), fmaxf(S[2][r], S[3][r]));
        #pragma unroll
        for (int s = 1; s < 16; s <<= 1) {
            #pragma unroll
            for (int r = 0; r < 4; ++r) rmax[r] = fmaxf(rmax[r], __shfl_xor(rmax[r], s));
        }
        #pragma unroll
        for (int r = 0; r < 4; ++r) {
            float mnew = fmaxf(mrun[r], rmax[r]);
            scale[r] = __expf(mrun[r] - mnew);
            mrun[r] = mnew;
            rs[r] = 0.f;
        }
        #pragma unroll
        for (int nt = 0; nt < 4; ++nt) {
            #pragma unroll
            for (int r = 0; r < 4; ++r) {
                float e = __expf(S[nt][r] - mrun[r]);
                S[nt][r] = e;
                rs[r] += e;
            }
        }
        #pragma unroll
        for (int s = 1; s < 16; s <<= 1) {
            #pragma unroll
            for (int r = 0; r < 4; ++r) rs[r] += __shfl_xor(rs[r], s);
        }
        #pragma unroll
        for (int r = 0; r < 4; ++r) lrun[r] = lrun[r] * scale[r] + rs[r];
        #pragma unroll
        for (int i = 0; i < 8; ++i) {
            #pragma unroll
            for (int r = 0; r < 4; ++r) yacc[i][r] *= scale[r];
        }
        // P -> wave-private LDS rows (same wave reads back; no barrier)
        #pragma unroll
        for (int nt = 0; nt < 4; ++nt) {
            #pragma unroll
            for (int r = 0; r < 4; ++r)
                s_p[(wrow + lh * 4 + r) * SP + nt * 16 + lr] = f2h_bits(S[nt][r]);
        }

        // ---- y += P * g
        f16x8 a_p[2];
        #pragma unroll
        for (int kc = 0; kc < 2; ++kc)
            a_p[kc] = *(const f16x8*)&s_p[(wrow + lr) * SP + kc * 32 + lh * 8];
        #pragma unroll
        for (int ct = 0; ct < 8; ++ct) {
            #pragma unroll
            for (int kc = 0; kc < 2; ++kc) {
                f16x8 bg = *(const f16x8*)&s_g[(ct * 16 + lr) * SG + kc * 32 + lh * 8];
                yacc[ct] = __builtin_amdgcn_mfma_f32_16x16x32_f16(a_p[kc], bg, yacc[ct], 0, 0, 0);
            }
        }
    }

    // ---- write unnormalized partial + (m,l) per row
    size_t pbase = ((size_t)(sx * B + b) * NN + row0 + wrow);
    #pragma unroll
    for (int ct = 0; ct < 8; ++ct) {
        #pragma unroll
        for (int r = 0; r < 4; ++r)
            yp[(pbase + lh * 4 + r) * CI + ct * 16 + lr] = f2h_bits(yacc[ct][r]);
    }
    if (lr == 0) {
        #pragma unroll
        for (int r = 0; r < 4; ++r) {
            float2 v; v.x = mrun[r]; v.y = lrun[r];
            ml[pbase + lh * 4 + r] = v;
        }
    }
}

// ---------------------------------------------------------------- K4: W conv (MFMA) + fused flash combine -> f16 wy + BN partials
__global__ __launch_bounds__(256) void k_wconv(const unsigned short* __restrict__ yp,
        const float2* __restrict__ ml, const unsigned short* __restrict__ wwh,
        const float* __restrict__ wb, unsigned short* __restrict__ wyh,
        float* __restrict__ psum, float* __restrict__ psq) {
    int blk = blockIdx.x;                  // 512 blocks of 64 n
    int b   = blk >> 6;
    int nloc = (blk & 63) * 64;
    int tid = threadIdx.x;
    int lane = tid & 63, wv = tid >> 6;
    int lr = lane & 15, lh = lane >> 4;

    f32x4 acc[4][4];
    #pragma unroll
    for (int i = 0; i < 4; ++i)
        #pragma unroll
        for (int j = 0; j < 4; ++j) acc[i][j] = (f32x4){0.f, 0.f, 0.f, 0.f};

    const unsigned short* y0b = yp + ((size_t)b * NN + nloc) * CI;
    const unsigned short* y1b = yp + ((size_t)(B + b) * NN + nloc) * CI;
    const float2* ml0 = ml + ((size_t)b * NN + nloc);
    const float2* ml1 = ml + ((size_t)(B + b) * NN + nloc);

    // per-row combine factors (row n = bt*16 + lr)
    float a0v[4], a1v[4];
    #pragma unroll
    for (int bt = 0; bt < 4; ++bt) {
        int n = bt * 16 + lr;
        float2 p0 = ml0[n], p1 = ml1[n];
        float M = fmaxf(p0.x, p1.x);
        float e0 = __expf(p0.x - M), e1 = __expf(p1.x - M);
        float L = e0 * p0.y + e1 * p1.y;
        a0v[bt] = e0 / L;
        a1v[bt] = e1 / L;
    }

    #pragma unroll
    for (int kc = 0; kc < 4; ++kc) {
        f16x8 a[4], bf[4];
        #pragma unroll
        for (int at = 0; at < 4; ++at)
            a[at] = *(const f16x8*)&wwh[(wv * 64 + at * 16 + lr) * CI + kc * 32 + lh * 8];
        #pragma unroll
        for (int bt = 0; bt < 4; ++bt) {
            size_t off = (size_t)(bt * 16 + lr) * CI + kc * 32 + lh * 8;
            f16x8 u0 = *(const f16x8*)&y0b[off];
            f16x8 u1 = *(const f16x8*)&y1b[off];
            f16x8 v;
            #pragma unroll
            for (int i = 0; i < 8; ++i)
                v[i] = (_Float16)(a0v[bt] * (float)u0[i] + a1v[bt] * (float)u1[i]);
            bf[bt] = v;
        }
        #pragma unroll
        for (int at = 0; at < 4; ++at)
            #pragma unroll
            for (int bt = 0; bt < 4; ++bt)
                acc[at][bt] = __builtin_amdgcn_mfma_f32_16x16x32_f16(a[at], bf[bt], acc[at][bt], 0, 0, 0);
    }
    #pragma unroll
    for (int at = 0; at < 4; ++at) {
        #pragma unroll
        for (int r = 0; r < 4; ++r) {
            int co = wv * 64 + at * 16 + lh * 4 + r;
            float bias = wb[co];
            unsigned short* wp = wyh + ((size_t)b * C + co) * NN + nloc;
            float sv = 0.f, q = 0.f;
            #pragma unroll
            for (int bt = 0; bt < 4; ++bt) {
                float v = acc[at][bt][r] + bias;
                wp[bt * 16 + lr] = f2h_bits(v);
                sv += v;
                q = fmaf(v, v, q);
            }
            #pragma unroll
            for (int o = 1; o < 16; o <<= 1) {
                sv += __shfl_xor(sv, o);
                q  += __shfl_xor(q, o);
            }
            if (lr == 0) {
                psum[co * 512 + blk] = sv;
                psq[co * 512 + blk]  = q;
            }
        }
    }
}

// ---------------------------------------------------------------- K4b: reduce BN partials
__global__ __launch_bounds__(64) void k_stats_r(const float* __restrict__ psum,
        const float* __restrict__ psq, float* __restrict__ stats) {
    int c = blockIdx.x;
    int lane = threadIdx.x;
    float s = 0.f, q = 0.f;
    #pragma unroll
    for (int k = 0; k < 8; ++k) {
        s += psum[c * 512 + lane + k * 64];
        q += psq[c * 512 + lane + k * 64];
    }
    #pragma unroll
    for (int o = 32; o >= 1; o >>= 1) {
        s += __shfl_down(s, o);
        q += __shfl_down(q, o);
    }
    if (lane == 0) { stats[c] = s; stats[256 + c] = q; }
}

// ---------------------------------------------------------------- K5: BN apply + residual (f16 wy input)
__global__ __launch_bounds__(256) void k_bn_out(const unsigned short* __restrict__ wyh,
        const float* __restrict__ x, const float* __restrict__ stats,
        const float* __restrict__ gamma, const float* __restrict__ beta,
        float* __restrict__ out) {
    size_t t = (size_t)blockIdx.x * 256 + threadIdx.x;   // 8-element groups
    size_t base = t * 8;
    int c = (int)((base >> 12) & 255);
    float mean = stats[c] * (1.f / 32768.f);
    float var  = stats[256 + c] * (1.f / 32768.f) - mean * mean;
    float sc = gamma[c] * rsqrtf(var + EPS);
    float sh = beta[c] - mean * sc;
    ushort4 w0 = *(const ushort4*)&wyh[base];
    ushort4 w1 = *(const ushort4*)&wyh[base + 4];
    float4 x0 = *(const float4*)&x[base];
    float4 x1 = *(const float4*)&x[base + 4];
    float4 o0, o1;
    o0.x = fmaf(h2f(w0.x), sc, sh) + x0.x;
    o0.y = fmaf(h2f(w0.y), sc, sh) + x0.y;
    o0.z = fmaf(h2f(w0.z), sc, sh) + x0.z;
    o0.w = fmaf(h2f(w0.w), sc, sh) + x0.w;
    o1.x = fmaf(h2f(w1.x), sc, sh) + x1.x;
    o1.y = fmaf(h2f(w1.y), sc, sh) + x1.y;
    o1.z = fmaf(h2f(w1.z), sc, sh) + x1.z;
    o1.w = fmaf(h2f(w1.w), sc, sh) + x1.w;
    *(float4*)&out[base]     = o0;
    *(float4*)&out[base + 4] = o1;
}

// ----------------------------------------------------------------
extern "C" void kernel_launch(void* const* d_in, const int* in_sizes, int n_in,
                              void* d_out, int out_size, void* d_ws, size_t ws_size,
                              hipStream_t stream) {
    const float* x    = (const float*)d_in[0];
    const float* g_w  = (const float*)d_in[1];
    const float* g_b  = (const float*)d_in[2];
    const float* th_w = (const float*)d_in[3];
    const float* th_b = (const float*)d_in[4];
    const float* ph_w = (const float*)d_in[5];
    const float* ph_b = (const float*)d_in[6];
    const float* w_w  = (const float*)d_in[7];
    const float* w_b  = (const float*)d_in[8];
    const float* bn_g = (const float*)d_in[9];
    const float* bn_b = (const float*)d_in[10];
    float* out = (float*)d_out;

    char* w0 = (char*)d_ws;
    unsigned short* xh    = (unsigned short*)w0;                 // [B][N][C] f16  16,777,216 B (dead after k_convs)
    unsigned short* yp    = (unsigned short*)w0;                 // [2][B][N][CI] f16 16,777,216 B (reuses xh)
    unsigned short* theta = (unsigned short*)(w0 + 16777216);    // [B][N][CI] f16   8,388,608 B
    unsigned short* wh    = (unsigned short*)(w0 + 25165824);    // 4x32768 f16        262,144 B
    unsigned short* twh   = wh;
    unsigned short* pwh   = wh + 32768;
    unsigned short* gwh   = wh + 65536;
    unsigned short* wwh   = wh + 98304;
    unsigned short* phi   = (unsigned short*)(w0 + 25427968);    // [B][m][CI] f16   2,097,152 B
    unsigned short* gx    = (unsigned short*)(w0 + 27525120);    // [B][CI][m] f16   2,097,152 B
    unsigned short* wyh   = (unsigned short*)(w0 + 38010880);    // [B][C][N]  f16  16,777,216 B
    float*          psum  = (float*)(w0 + 54788096);             // [256][512] f32     524,288 B
    float*          psq   = (float*)(w0 + 55312384);             // [256][512] f32     524,288 B
    float*          stats = (float*)(w0 + 55836672);             // 512 f32
    float2*         ml    = (float2*)(w0 + 55840768);            // [2][B][N] float2   524,288 B

    k_xt<<<dim3(65, 4, B), 256, 0, stream>>>(x, xh, th_w, ph_w, g_w, w_w, wh);
    k_convs<<<256, 512, 0, stream>>>(xh, twh, pwh, gwh, th_b, ph_b, g_b, theta, phi, gx);
    k_attn_mfma<<<dim3(64, B, 2), 256, 0, stream>>>(theta, phi, gx, yp, ml);
    k_wconv<<<512, 256, 0, stream>>>(yp, ml, wwh, w_b, wyh, psum, psq);
    k_stats_r<<<256, 64, 0, stream>>>(psum, psq, stats);
    k_bn_out<<<4096, 256, 0, stream>>>(wyh, x, stats, bn_g, bn_b, out);
}